// Round 1
// baseline (9492.176 us; speedup 1.0000x reference)
//
#include <hip/hip_runtime.h>
#include <cstdint>
#include <cstddef>

// Problem constants
#define BATCH   256
#define NDIM    64
#define NUMM    50000
#define NUMT    4096
#define NGEN    2016
#define STEPS   50

// ---------------- helpers ----------------

__device__ __forceinline__ unsigned long long okey(double x){
  unsigned long long b = (unsigned long long)__double_as_longlong(x);
  return (b & 0x8000000000000000ull) ? ~b : (b | 0x8000000000000000ull);
}

// ---------------- k_embs: row-normalize embeddings ----------------
__global__ void k_embs(const float* __restrict__ emb, float* __restrict__ out){
  int wid = (int)(((size_t)blockIdx.x * 256 + threadIdx.x) >> 6);
  int lane = threadIdx.x & 63;
  if (wid >= NUMM) return;
  float x = emb[(size_t)wid * 64 + lane];
  float ss = x * x;
  #pragma unroll
  for (int m = 32; m; m >>= 1) ss += __shfl_xor(ss, m);
  float n = fmaxf(sqrtf(ss), 1e-12f);
  out[(size_t)wid * 64 + lane] = x / n;
}

// ---------------- k_idx: find one-hot indices ----------------
__global__ void k_idx(const float* __restrict__ vsrc, const float* __restrict__ vtgt,
                      int* __restrict__ idx){
  int b = blockIdx.x;
  const float* row = (b < BATCH) ? (vsrc + (size_t)b * NUMM) : (vtgt + (size_t)(b - BATCH) * NUMM);
  for (int m = threadIdx.x; m < NUMM; m += 256)
    if (row[m] > 0.5f) idx[b] = m;
}

// ---------------- k_gather: v0/vt gather + zero control state ----------------
__global__ void k_gather(const float* __restrict__ embs, const int* __restrict__ idx,
                         float* __restrict__ v0, float* __restrict__ vt,
                         unsigned long long* __restrict__ amax, unsigned* __restrict__ cnt,
                         float* __restrict__ psum){
  int g = blockIdx.x * 256 + threadIdx.x;   // grid 128 -> 32768 threads
  if (g < BATCH * 64){
    int b = g >> 6, c = g & 63;
    v0[g] = embs[(size_t)idx[b] * 64 + c];
    vt[g] = embs[(size_t)idx[BATCH + b] * 64 + c];
  }
  for (int i = g; i < STEPS * BATCH; i += 32768) amax[i] = 0ull;
  if (g == 0) cnt[0] = 0u;
  if (g < BATCH) psum[g] = 0.f;
}

// ---------------- 64x64 matmul in LDS: C[i][j] = sum_k s*L[k][i]*B[k][j] ----------------
// (left operand indexed transposed: valid because A is exactly skew (s=-1) or operand is
//  exactly symmetric (s=+1) -> both sides read row-contiguous, bank-conflict-free)
template<int NEG>
__device__ __forceinline__ void mm64(const float* __restrict__ L,
                                     const float* __restrict__ Bm,
                                     float* __restrict__ C){
  const int ti = (threadIdx.x >> 4) << 2;
  const int tj = (threadIdx.x & 15) << 2;
  float4 c0 = make_float4(0.f,0.f,0.f,0.f), c1 = c0, c2 = c0, c3 = c0;
  #pragma unroll 8
  for (int k = 0; k < 64; ++k){
    float4 a = *(const float4*)(L + (k << 6) + ti);
    float4 b = *(const float4*)(Bm + (k << 6) + tj);
    if (NEG){ a.x = -a.x; a.y = -a.y; a.z = -a.z; a.w = -a.w; }
    c0.x = fmaf(a.x,b.x,c0.x); c0.y = fmaf(a.x,b.y,c0.y); c0.z = fmaf(a.x,b.z,c0.z); c0.w = fmaf(a.x,b.w,c0.w);
    c1.x = fmaf(a.y,b.x,c1.x); c1.y = fmaf(a.y,b.y,c1.y); c1.z = fmaf(a.y,b.z,c1.z); c1.w = fmaf(a.y,b.w,c1.w);
    c2.x = fmaf(a.z,b.x,c2.x); c2.y = fmaf(a.z,b.y,c2.y); c2.z = fmaf(a.z,b.z,c2.z); c2.w = fmaf(a.z,b.w,c2.w);
    c3.x = fmaf(a.w,b.x,c3.x); c3.y = fmaf(a.w,b.y,c3.y); c3.z = fmaf(a.w,b.z,c3.z); c3.w = fmaf(a.w,b.w,c3.w);
  }
  *(float4*)(C + (ti + 0) * 64 + tj) = c0;
  *(float4*)(C + (ti + 1) * 64 + tj) = c1;
  *(float4*)(C + (ti + 2) * 64 + tj) = c2;
  *(float4*)(C + (ti + 3) * 64 + tj) = c3;
  __syncthreads();
}

// ---------------- k_expm: R[t] = expm(G[t]) exactly mirroring jax pade7 path ----------------
__launch_bounds__(256, 2)
__global__ void k_expm(const float* __restrict__ coeffs, float* __restrict__ Rall){
  extern __shared__ float lds[];
  float* Am  = lds;           // A (16KB), later GJ scratch
  float* R2  = lds + 4096;    // A2 -> U
  float* R3  = lds + 8192;    // A4
  float* R4a = lds + 12288;   // A6 -> S -> X
  float* R4b = lds + 16384;   // V  -> XT
  const int t = blockIdx.x;
  const int tid = threadIdx.x;

  // build skew A from coeffs (triu row-major ordering)
  for (int e = tid; e < 4096; e += 256) Am[e] = 0.f;
  __syncthreads();
  for (int gi = tid; gi < NGEN; gi += 256){
    int i = (int)((127.0 - sqrt(16129.0 - 8.0 * (double)gi)) * 0.5);
    while ((i+1)*64 - (((i+1)*(i+2)) >> 1) <= gi) ++i;
    while (i*64 - ((i*(i+1)) >> 1) > gi) --i;
    int j = i + 1 + (gi - (i*64 - ((i*(i+1)) >> 1)));
    float c = coeffs[(size_t)t * NGEN + gi];
    Am[i*64 + j] = -c;
    Am[j*64 + i] =  c;
  }
  __syncthreads();

  // A_L1 (col sums == row sums of |A| by skewness), n_squarings, scale
  if (tid < 64){
    float s = 0.f;
    #pragma unroll
    for (int j4 = 0; j4 < 16; ++j4){
      float4 a = *(const float4*)(Am + tid*64 + (j4 << 2));
      s += fabsf(a.x) + fabsf(a.y) + fabsf(a.z) + fabsf(a.w);
    }
    #pragma unroll
    for (int m = 32; m; m >>= 1) s = fmaxf(s, __shfl_xor(s, m));
    if (tid == 0){
      float ratio = s / 3.925724783138660f;
      int k = (int)floorf(log2f(ratio));
      if (!(k > 0)) k = 0;
      if (k > 16) k = 16;
      R2[0] = exp2f((float)(-k));
      ((int*)R2)[1] = k;
    }
  }
  __syncthreads();
  const float scale = R2[0];
  const int nsq = ((int*)R2)[1];
  __syncthreads();
  for (int e = tid; e < 4096; e += 256) Am[e] *= scale;
  __syncthreads();

  mm64<1>(Am, Am, R2);   // A2
  mm64<0>(R2, R2, R3);   // A4
  mm64<0>(R3, R2, R4a);  // A6
  // V (direct formula) and S (in place over A6)
  for (int e = tid; e < 4096; e += 256){
    float a2 = R2[e], a4 = R3[e], a6 = R4a[e];
    float d = ((e >> 6) == (e & 63)) ? 1.f : 0.f;
    R4b[e] = 56.f*a6 + 25200.f*a4 + 1995840.f*a2 + 17297280.f*d;     // V
    R4a[e] = a6 + 1512.f*a4 + 277200.f*a2 + 8648640.f*d;             // S
  }
  __syncthreads();
  mm64<1>(Am, R4a, R2);  // U = A @ S  (into dead A2)

  // load [Q|P] into registers: Q = V-U, P = V+U
  const int tr = tid >> 5, tc = tid & 31;
  float q[8][4];
  {
    const int cc = (tc << 2) & 63;
    const bool isQ = (tc < 16);
    #pragma unroll
    for (int a = 0; a < 8; ++a){
      int row = tr + (a << 3);
      float4 u4 = *(const float4*)(R2  + row*64 + cc);
      float4 v4 = *(const float4*)(R4b + row*64 + cc);
      if (isQ){ q[a][0]=v4.x-u4.x; q[a][1]=v4.y-u4.y; q[a][2]=v4.z-u4.z; q[a][3]=v4.w-u4.w; }
      else    { q[a][0]=v4.x+u4.x; q[a][1]=v4.y+u4.y; q[a][2]=v4.z+u4.z; q[a][3]=v4.w+u4.w; }
    }
  }
  __syncthreads();

  // Gauss-Jordan with partial (virtual) pivoting; matrix in regs, scratch in dead A
  float* fcol   = Am;
  float* pivrow = Am + 64;
  float* reda   = Am + 192;
  float* redv   = Am + 200;
  int*   redi   = (int*)(Am + 208);
  float* pinv   = Am + 216;
  int*   prowp  = (int*)(Am + 220);
  int*   pstep  = (int*)(Am + 224);
  unsigned pivmask = 0u;
  #pragma unroll 1
  for (int r = 0; r < 64; ++r){
    const int rb = r & 3;
    const bool own = (tc == (r >> 2));
    if (own){
      float bav = -1.f, bv = 1.f; int brow = 0;
      #pragma unroll
      for (int a = 0; a < 8; ++a){
        float v = (rb==0)?q[a][0]:(rb==1)?q[a][1]:(rb==2)?q[a][2]:q[a][3];
        float av = fabsf(v);
        bool tk = (((pivmask >> a) & 1u) == 0u) && (av > bav);
        bav = tk ? av : bav; bv = tk ? v : bv; brow = tk ? (tr + (a << 3)) : brow;
      }
      reda[tr] = bav; redv[tr] = bv; redi[tr] = brow;
    }
    __syncthreads();
    if (tid == 0){
      float ba = reda[0], bsv = redv[0]; int br = redi[0];
      #pragma unroll
      for (int x = 1; x < 8; ++x)
        if (reda[x] > ba){ ba = reda[x]; bsv = redv[x]; br = redi[x]; }
      prowp[0] = br; pinv[0] = 1.0f / bsv; pstep[br] = r;
    }
    __syncthreads();
    const int prow = prowp[0];
    const float pivinv = pinv[0];
    if ((prow & 7) == tr) pivmask |= (1u << (prow >> 3));
    if (own){  // factor column (pre-scale values); pivot-row entry unused later
      #pragma unroll
      for (int a = 0; a < 8; ++a){
        float v = (rb==0)?q[a][0]:(rb==1)?q[a][1]:(rb==2)?q[a][2]:q[a][3];
        fcol[tr + (a << 3)] = v;
      }
    }
    if ((prow & 7) == tr){  // scale pivot row, publish it
      const int pa = prow >> 3;
      #pragma unroll
      for (int a = 0; a < 8; ++a){
        if (a == pa){
          q[a][0] *= pivinv; q[a][1] *= pivinv; q[a][2] *= pivinv; q[a][3] *= pivinv;
          pivrow[(tc << 2) + 0] = q[a][0];
          pivrow[(tc << 2) + 1] = q[a][1];
          pivrow[(tc << 2) + 2] = q[a][2];
          pivrow[(tc << 2) + 3] = q[a][3];
        }
      }
    }
    __syncthreads();
    const bool act = (tc >= 16) || ((tc << 2) + 3 >= r);
    if (act){
      float4 pv = *(const float4*)(pivrow + (tc << 2));
      #pragma unroll
      for (int a = 0; a < 8; ++a){
        int row = tr + (a << 3);
        float f = fcol[row];
        f = (row == prow) ? 0.f : f;
        q[a][0] = fmaf(-f, pv.x, q[a][0]);
        q[a][1] = fmaf(-f, pv.y, q[a][1]);
        q[a][2] = fmaf(-f, pv.z, q[a][2]);
        q[a][3] = fmaf(-f, pv.w, q[a][3]);
      }
    }
    __syncthreads();
  }
  // scatter solution X (P columns, rows permuted by pivot order) into R4a
  if (tc >= 16){
    const int c0 = (tc - 16) << 2;
    #pragma unroll
    for (int a = 0; a < 8; ++a){
      int row = tr + (a << 3);
      int xr = pstep[row];
      *(float4*)(R4a + xr*64 + c0) = make_float4(q[a][0], q[a][1], q[a][2], q[a][3]);
    }
  }
  __syncthreads();
  if (nsq > 0){
    for (int e = tid; e < 4096; e += 256) R4b[(e & 63)*64 + (e >> 6)] = R4a[e];
    __syncthreads();
    for (int it = 0; it < nsq; ++it){
      mm64<0>(R4b, R4a, R2);  // X @ X
      for (int e = tid; e < 4096; e += 256){
        float v = R2[e];
        R4a[e] = v;
        R4b[(e & 63)*64 + (e >> 6)] = v;
      }
      __syncthreads();
    }
  }
  float* Ro = Rall + ((size_t)t << 12);
  for (int e = tid; e < 1024; e += 256)
    *(float4*)(Ro + (e << 2)) = *(const float4*)(R4a + (e << 2));
}

// ---------------- k_scan: 50-step cooperative scan ----------------
// grid 256 = 64 b-tiles (4 batch each) x 4 t-slices (1024 logits each); one wave per batch row
__launch_bounds__(256, 1)
__global__ void k_scan(const float* __restrict__ W1, const float* __restrict__ b1,
                       const float* __restrict__ W2, const float* __restrict__ b2,
                       const float* __restrict__ W3, const float* __restrict__ b3,
                       const float* __restrict__ gum, const float* __restrict__ Rall,
                       const float* __restrict__ v0, const float* __restrict__ vt,
                       float* __restrict__ vfinal, unsigned long long* __restrict__ amax,
                       unsigned* __restrict__ cnt, float* __restrict__ outL){
  __shared__ float  hT[128][4];    // rows 0..63: v_cur, rows 64..127: v_tgt (constant)
  __shared__ float  h1T[256][4];
  __shared__ double h2T[128][4];
  const int tid = threadIdx.x;
  const int bt = (int)blockIdx.x & 63;
  const int tt = (int)blockIdx.x >> 6;
  const int b0 = bt << 2;
  const int t0 = tt << 10;
  const int wv = tid >> 6;      // local batch row (one wave each)
  const int lane = tid & 63;
  for (int e = tid; e < 256; e += 256){
    int c = e >> 2, bb = e & 3;
    hT[c][bb]      = v0[(b0 + bb)*64 + c];
    hT[64 + c][bb] = vt[(b0 + bb)*64 + c];
  }
  __syncthreads();
  #pragma unroll 1
  for (int s = 0; s < STEPS; ++s){
    if (s > 0){
      // v <- normalize(R[t*_{s-1}] @ v)
      unsigned long long pk = __hip_atomic_load(&amax[(s-1)*BATCH + b0 + wv],
                                                __ATOMIC_ACQUIRE, __HIP_MEMORY_SCOPE_AGENT);
      int tp = 4095 - (int)(pk & 0xFFFull);
      const float* Rr = Rall + ((size_t)tp << 12) + (lane << 6);
      float acc = 0.f;
      #pragma unroll
      for (int j4 = 0; j4 < 16; ++j4){
        float4 r4 = *(const float4*)(Rr + (j4 << 2));
        acc = fmaf(r4.x, hT[(j4<<2)+0][wv], acc);
        acc = fmaf(r4.y, hT[(j4<<2)+1][wv], acc);
        acc = fmaf(r4.z, hT[(j4<<2)+2][wv], acc);
        acc = fmaf(r4.w, hT[(j4<<2)+3][wv], acc);
      }
      float s2 = acc * acc;
      #pragma unroll
      for (int m = 32; m; m >>= 1) s2 += __shfl_xor(s2, m);
      float nv = acc / fmaxf(sqrtf(s2), 1e-12f);
      hT[lane][wv] = nv;   // lockstep wave: all reads precede writes; columns disjoint per wave
      __syncthreads();
    }
    { // L1: 256 outputs, 4 batch rows each
      const int o = tid;
      float a0=0.f, a1=0.f, a2=0.f, a3=0.f;
      #pragma unroll 8
      for (int k = 0; k < 128; ++k){
        float w = W1[(k << 8) + o];
        float4 h4 = *(const float4*)&hT[k][0];
        a0 = fmaf(w, h4.x, a0); a1 = fmaf(w, h4.y, a1);
        a2 = fmaf(w, h4.z, a2); a3 = fmaf(w, h4.w, a3);
      }
      float bb = b1[o];
      h1T[o][0] = fmaxf(a0 + bb, 0.f);
      h1T[o][1] = fmaxf(a1 + bb, 0.f);
      h1T[o][2] = fmaxf(a2 + bb, 0.f);
      h1T[o][3] = fmaxf(a3 + bb, 0.f);
    }
    __syncthreads();
    if (tid < 128){ // L2
      const int o = tid;
      float a0=0.f, a1=0.f, a2=0.f, a3=0.f;
      #pragma unroll 8
      for (int k = 0; k < 256; ++k){
        float w = W2[(k << 7) + o];
        float4 h4 = *(const float4*)&h1T[k][0];
        a0 = fmaf(w, h4.x, a0); a1 = fmaf(w, h4.y, a1);
        a2 = fmaf(w, h4.z, a2); a3 = fmaf(w, h4.w, a3);
      }
      float bb = b2[o];
      h2T[o][0] = (double)fmaxf(a0 + bb, 0.f);
      h2T[o][1] = (double)fmaxf(a1 + bb, 0.f);
      h2T[o][2] = (double)fmaxf(a2 + bb, 0.f);
      h2T[o][3] = (double)fmaxf(a3 + bb, 0.f);
    }
    __syncthreads();
    { // L3 (f64 accumulate) + logits write + argmax atomics
      const int b = b0 + wv;
      double acc[4][4];
      #pragma unroll
      for (int c = 0; c < 4; ++c){ acc[c][0]=0.0; acc[c][1]=0.0; acc[c][2]=0.0; acc[c][3]=0.0; }
      const float* W3p = W3 + t0 + (lane << 2);
      #pragma unroll 2
      for (int k = 0; k < 128; ++k){
        double h = h2T[k][wv];
        const float* wr = W3p + ((size_t)k << 12);
        #pragma unroll
        for (int c = 0; c < 4; ++c){
          float4 w4 = *(const float4*)(wr + (c << 8));
          acc[c][0] = fma(h, (double)w4.x, acc[c][0]);
          acc[c][1] = fma(h, (double)w4.y, acc[c][1]);
          acc[c][2] = fma(h, (double)w4.z, acc[c][2]);
          acc[c][3] = fma(h, (double)w4.w, acc[c][3]);
        }
      }
      float* op = outL + (size_t)b * (STEPS*NUMT) + (size_t)s * NUMT + t0 + (lane << 2);
      const float* gp = gum + (((size_t)s * BATCH + b) << 12) + t0 + (lane << 2);
      const float* bp = b3 + t0 + (lane << 2);
      unsigned long long best = 0ull;
      #pragma unroll
      for (int c = 0; c < 4; ++c){
        float4 b4 = *(const float4*)(bp + (c << 8));
        float4 g4 = *(const float4*)(gp + (c << 8));
        double l0 = acc[c][0] + (double)b4.x;
        double l1 = acc[c][1] + (double)b4.y;
        double l2 = acc[c][2] + (double)b4.z;
        double l3 = acc[c][3] + (double)b4.w;
        *(float4*)(op + (c << 8)) = make_float4((float)l0, (float)l1, (float)l2, (float)l3);
        int tg = t0 + (lane << 2) + (c << 8);
        unsigned long long p0 = (okey(l0 + (double)g4.x) & 0xFFFFFFFFFFFFF000ull) | (unsigned long long)(4095 - (tg+0));
        unsigned long long p1 = (okey(l1 + (double)g4.y) & 0xFFFFFFFFFFFFF000ull) | (unsigned long long)(4095 - (tg+1));
        unsigned long long p2 = (okey(l2 + (double)g4.z) & 0xFFFFFFFFFFFFF000ull) | (unsigned long long)(4095 - (tg+2));
        unsigned long long p3 = (okey(l3 + (double)g4.w) & 0xFFFFFFFFFFFFF000ull) | (unsigned long long)(4095 - (tg+3));
        best = p0 > best ? p0 : best;
        best = p1 > best ? p1 : best;
        best = p2 > best ? p2 : best;
        best = p3 > best ? p3 : best;
      }
      #pragma unroll
      for (int m = 32; m; m >>= 1){
        unsigned long long ob = __shfl_xor(best, m);
        best = ob > best ? ob : best;
      }
      if (lane == 0) atomicMax(&amax[s*BATCH + b], best);
    }
    // grid barrier (monotone counter; cross-block data is atomics-only -> coherent)
    __syncthreads();
    if (tid == 0){
      __threadfence();
      __hip_atomic_fetch_add(cnt, 1u, __ATOMIC_ACQ_REL, __HIP_MEMORY_SCOPE_AGENT);
      unsigned want = (unsigned)(s + 1) * gridDim.x;
      while (__hip_atomic_load(cnt, __ATOMIC_ACQUIRE, __HIP_MEMORY_SCOPE_AGENT) < want)
        __builtin_amdgcn_s_sleep(8);
    }
    __syncthreads();
  }
  { // final rotate -> v_final
    unsigned long long pk = __hip_atomic_load(&amax[(STEPS-1)*BATCH + b0 + wv],
                                              __ATOMIC_ACQUIRE, __HIP_MEMORY_SCOPE_AGENT);
    int tp = 4095 - (int)(pk & 0xFFFull);
    const float* Rr = Rall + ((size_t)tp << 12) + (lane << 6);
    float acc = 0.f;
    #pragma unroll
    for (int j4 = 0; j4 < 16; ++j4){
      float4 r4 = *(const float4*)(Rr + (j4 << 2));
      acc = fmaf(r4.x, hT[(j4<<2)+0][wv], acc);
      acc = fmaf(r4.y, hT[(j4<<2)+1][wv], acc);
      acc = fmaf(r4.z, hT[(j4<<2)+2][wv], acc);
      acc = fmaf(r4.w, hT[(j4<<2)+3][wv], acc);
    }
    float s2 = acc * acc;
    #pragma unroll
    for (int m = 32; m; m >>= 1) s2 += __shfl_xor(s2, m);
    float nv = acc / fmaxf(sqrtf(s2), 1e-12f);
    vfinal[(b0 + wv)*64 + lane] = nv;
  }
}

// ---------------- k_pred: z = vf @ embs^T, exp, partial sums ----------------
__launch_bounds__(256, 2)
__global__ void k_pred(const float* __restrict__ embs, const float* __restrict__ vf,
                       float* __restrict__ out, float* __restrict__ psum){
  __shared__ float ech[32][64];
  __shared__ float zt[256][33];
  const int tid = threadIdx.x;
  const int m0 = (int)blockIdx.x << 8;
  float v[64];
  #pragma unroll
  for (int k4 = 0; k4 < 16; ++k4){
    float4 t4 = *(const float4*)(vf + (tid << 6) + (k4 << 2));
    v[(k4<<2)+0] = t4.x; v[(k4<<2)+1] = t4.y; v[(k4<<2)+2] = t4.z; v[(k4<<2)+3] = t4.w;
  }
  float sexp = 0.f;
  for (int ch = 0; ch < 8; ++ch){
    const int mb = m0 + (ch << 5);
    __syncthreads();
    for (int e = tid; e < 2048; e += 256){
      int mm = e >> 6, kk = e & 63;
      int mg = mb + mm;
      ech[mm][kk] = (mg < NUMM) ? embs[(size_t)mg*64 + kk] : 0.f;
    }
    __syncthreads();
    #pragma unroll 1
    for (int mm = 0; mm < 32; ++mm){
      float acc = 0.f;
      #pragma unroll
      for (int k4 = 0; k4 < 16; ++k4){
        float4 e4 = *(const float4*)&ech[mm][k4 << 2];
        acc = fmaf(v[(k4<<2)+0], e4.x, acc);
        acc = fmaf(v[(k4<<2)+1], e4.y, acc);
        acc = fmaf(v[(k4<<2)+2], e4.z, acc);
        acc = fmaf(v[(k4<<2)+3], e4.w, acc);
      }
      float ex = __expf(acc);   // |z|<=1 so max-subtraction is unnecessary
      zt[tid][mm] = ex;
      if (mb + mm < NUMM) sexp += ex;
    }
    __syncthreads();
    const int q8 = tid >> 5, j = tid & 31;
    const int mg = mb + j;
    if (mg < NUMM){
      #pragma unroll 4
      for (int bb = 0; bb < 32; ++bb){
        int b = (q8 << 5) + bb;
        out[(size_t)b*NUMM + mg] = zt[b][j];
      }
    }
  }
  atomicAdd(&psum[tid], sexp);
}

// ---------------- k_scale: normalize softmax ----------------
__global__ void k_scale(float* __restrict__ out, const float* __restrict__ psum){
  size_t i = (size_t)blockIdx.x * 256 + threadIdx.x;
  size_t stride = (size_t)gridDim.x * 256;
  for (; i < (size_t)BATCH * NUMM; i += stride){
    int b = (int)(i / NUMM);
    out[i] = out[i] / psum[b];
  }
}

// ---------------- launch ----------------
extern "C" void kernel_launch(void* const* d_in, const int* in_sizes, int n_in,
                              void* d_out, int out_size, void* d_ws, size_t ws_size,
                              hipStream_t stream) {
  const float* vsrc = (const float*)d_in[0];
  const float* vtgt = (const float*)d_in[1];
  const float* emb  = (const float*)d_in[2];
  const float* tcf  = (const float*)d_in[3];
  const float* W1   = (const float*)d_in[4];
  const float* b1   = (const float*)d_in[5];
  const float* W2   = (const float*)d_in[6];
  const float* b2   = (const float*)d_in[7];
  const float* W3   = (const float*)d_in[8];
  const float* b3   = (const float*)d_in[9];
  const float* gum  = (const float*)d_in[10];
  float* out = (float*)d_out;
  float* ws  = (float*)d_ws;

  // ws layout (float offsets); total ~80.2 MB
  float* embs = ws;                              // 3,200,000
  float* Rall = ws + 3200000;                    // 16,777,216
  int*   idx  = (int*)(ws + 19977216);           // 512
  float* v0   = ws + 19977728;                   // 16384
  float* vt   = ws + 19994112;                   // 16384
  float* vf   = ws + 20010496;                   // 16384
  unsigned long long* amax = (unsigned long long*)(ws + 20026880); // 12800 u64
  unsigned* cnt = (unsigned*)(ws + 20052480);
  float* psum = ws + 20052608;                   // 256

  hipFuncSetAttribute(reinterpret_cast<const void*>(k_expm),
                      hipFuncAttributeMaxDynamicSharedMemorySize, 81920);

  k_embs  <<<12500, 256, 0, stream>>>(emb, embs);
  k_idx   <<<512,   256, 0, stream>>>(vsrc, vtgt, idx);
  k_gather<<<128,   256, 0, stream>>>(embs, idx, v0, vt, amax, cnt, psum);
  k_expm  <<<4096,  256, 81920, stream>>>(tcf, Rall);
  k_scan  <<<256,   256, 0, stream>>>(W1, b1, W2, b2, W3, b3, gum, Rall,
                                      v0, vt, vf, amax, cnt, out + 12800000);
  k_pred  <<<196,   256, 0, stream>>>(embs, vf, out, psum);
  k_scale <<<2048,  256, 0, stream>>>(out, psum);
}